// Round 1
// baseline (135.114 us; speedup 1.0000x reference)
//
#include <hip/hip_runtime.h>

#define BB 8
#define NN 256
#define FF 59
#define CC 128
#define EPSV 1e-5f

// ws layout (floats)
#define WS_V     0
#define WS_ASRC  (WS_V + BB*NN*CC)
#define WS_ADST  (WS_ASRC + BB*NN*CC)
#define WS_PWT   (WS_ADST + BB*NN*CC)
#define WS_T1    (WS_PWT + 6*CC)
#define WS_T2    (WS_T1 + CC)
#define WS_WT    (WS_T2 + CC)

// blocks 0..383: projections (type = blk>>7: 0=v/W_lin, 1=a_src/W_src, 2=a_dst/W_dst)
// block  384   : fold BN into pos_w (-> pwt transposed, T1) and attn_w (-> wt transposed, T2)
__global__ __launch_bounds__(256) void prep_kernel(
    const float* __restrict__ x, const float* __restrict__ W_lin,
    const float* __restrict__ W_src, const float* __restrict__ W_dst,
    const float* __restrict__ pos_w, const float* __restrict__ pos_b,
    const float* __restrict__ pos_g, const float* __restrict__ pos_bb,
    const float* __restrict__ pos_m, const float* __restrict__ pos_v,
    const float* __restrict__ attn_w, const float* __restrict__ attn_b,
    const float* __restrict__ attn_g, const float* __restrict__ attn_bb,
    const float* __restrict__ attn_m, const float* __restrict__ attn_v,
    float* __restrict__ ws)
{
    int blk = blockIdx.x;
    int tid = threadIdx.x;
    if (blk < 384) {
        int type = blk >> 7;
        int g    = blk & 127;
        int b    = g >> 4;
        int n0   = (g & 15) * 16;
        const float* W = (type == 0) ? W_lin : (type == 1) ? W_src : W_dst;
        float* outp = ws + ((type == 0) ? WS_V : (type == 1) ? WS_ASRC : WS_ADST);
        __shared__ float Wl[CC * FF];   // 30208 B
        __shared__ float xs[16 * FF];   //  3776 B
        for (int idx = tid; idx < CC * FF; idx += 256) Wl[idx] = W[idx];
        const float* xrow = x + (size_t)(b * NN + n0) * FF;
        for (int idx = tid; idx < 16 * FF; idx += 256) xs[idx] = xrow[idx];
        __syncthreads();
        int c = tid & 127, h = tid >> 7;
        float acc[8];
#pragma unroll
        for (int q = 0; q < 8; ++q) acc[q] = 0.f;
        for (int f = 0; f < FF; ++f) {
            float w = Wl[c * FF + f];
#pragma unroll
            for (int q = 0; q < 8; ++q) acc[q] += w * xs[(h * 8 + q) * FF + f];
        }
#pragma unroll
        for (int q = 0; q < 8; ++q) {
            int n = n0 + h * 8 + q;
            outp[(b * NN + n) * CC + c] = acc[q];
        }
    } else {
        __shared__ float S2s[CC];
        if (tid < CC) {
            int c = tid;
            float S1 = rsqrtf(pos_v[c] + EPSV) * pos_g[c];
            ws[WS_T1 + c] = (pos_b[c] - pos_m[c]) * S1 + pos_bb[c];
#pragma unroll
            for (int k = 0; k < 6; ++k) ws[WS_PWT + k * CC + c] = pos_w[c * 6 + k] * S1;
            float S2 = rsqrtf(attn_v[c] + EPSV) * attn_g[c];
            S2s[c] = S2;
            ws[WS_T2 + c] = (attn_b[c] - attn_m[c]) * S2 + attn_bb[c];
        }
        __syncthreads();
        for (int idx = tid; idx < CC * CC; idx += 256) {
            int d = idx & 127, cc2 = idx >> 7;
            ws[WS_WT + cc2 * CC + d] = attn_w[d * CC + cc2] * S2s[d];
        }
    }
}

// One block per (b, i). Compact valid j's (dist2 <= r^2), then tiles of 16 j:
// phase1: delta/alpha/u -> LDS; phase2: scores matmul (d per lane, 8 j per thread);
// phase3: streaming exp-sum (no max subtraction needed: scores in [0, ~60]).
__global__ __launch_bounds__(256) void main_kernel(
    const float* __restrict__ pos, const float* __restrict__ nrm,
    const int* __restrict__ rptr, const float* __restrict__ ws,
    float* __restrict__ out)
{
    const float* v    = ws + WS_V;
    const float* asrc = ws + WS_ASRC;
    const float* adst = ws + WS_ADST;
    const float* pwt  = ws + WS_PWT;
    const float* T1   = ws + WS_T1;
    const float* T2   = ws + WS_T2;
    const float* wt   = ws + WS_WT;

    int blk = blockIdx.x;
    int b = blk >> 8, i = blk & 255;
    int tid = threadIdx.x;

    __shared__ float relf[NN * 6];
    __shared__ int   jlist[NN];
    __shared__ int   wcnt[4];
    __shared__ int   cnt_s;
    __shared__ float alpha_t[CC * 20];   // [c][slot], stride 20 (16B-aligned float4 at +0/+8)
    __shared__ float u_lds[16 * CC];     // [slot][d]
    __shared__ float sered[CC], ored[CC];

    int rv = rptr[0];
    float r2 = (float)(rv * rv);
    const float* pib = pos + (size_t)(b * NN + i) * 3;
    const float* nib = nrm + (size_t)(b * NN + i) * 3;
    float pix = pib[0], piy = pib[1], piz = pib[2];
    float nix = nib[0], niy = nib[1], niz = nib[2];
    {
        int j = tid;
        const float* pj = pos + (size_t)(b * NN + j) * 3;
        const float* nj = nrm + (size_t)(b * NN + j) * 3;
        float dx = pix - pj[0], dy = piy - pj[1], dz = piz - pj[2];
        float ex = nix - nj[0], ey = niy - nj[1], ez = niz - nj[2];
        float d2 = dx * dx + dy * dy + dz * dz;
        bool valid = (d2 <= r2);
        unsigned long long m = __ballot(valid);
        int w = tid >> 6, lane = tid & 63;
        if (lane == 0) wcnt[w] = __popcll(m);
        __syncthreads();
        int off = 0;
        for (int w2 = 0; w2 < w; ++w2) off += wcnt[w2];
        if (tid == 0) cnt_s = wcnt[0] + wcnt[1] + wcnt[2] + wcnt[3];
        int rank = __popcll(m & ((1ull << lane) - 1ull));
        if (valid) {
            int s = off + rank;
            jlist[s] = j;
            relf[s * 6 + 0] = dx; relf[s * 6 + 1] = dy; relf[s * 6 + 2] = dz;
            relf[s * 6 + 3] = ex; relf[s * 6 + 4] = ey; relf[s * 6 + 5] = ez;
        }
    }
    __syncthreads();
    int cnt = cnt_s;   // >= 1 (self-loop)

    int c    = tid & 127;   // channel lane (both c-role in phase1 and d-role in phase2)
    int half = tid >> 7;

    float pw[6];
#pragma unroll
    for (int k = 0; k < 6; ++k) pw[k] = pwt[k * CC + c];
    float T1c    = T1[c];
    float T2d    = T2[c];
    float adst_c = adst[(b * NN + i) * CC + c];

    float se = 0.f, ov = 0.f;

    for (int base = 0; base < cnt; base += 16) {
        int tcnt = min(16, cnt - base);
        // ---- phase 1: delta/alpha/u for this tile ----
#pragma unroll
        for (int q = 0; q < 8; ++q) {
            int js = half * 8 + q;
            float aval = 0.f, uval = 0.f;
            if (js < tcnt) {
                int j = jlist[base + js];
                const float* rf = &relf[(base + js) * 6];
                float dsum = T1c;
#pragma unroll
                for (int k = 0; k < 6; ++k) dsum += pw[k] * rf[k];
                float delta = fmaxf(dsum, 0.f);
                float as = asrc[(b * NN + j) * CC + c];
                float vv = v[(b * NN + j) * CC + c];
                aval = adst_c - as + delta;
                uval = vv + delta;
            }
            alpha_t[c * 20 + js] = aval;
            u_lds[js * CC + c]   = uval;
        }
        __syncthreads();
        // ---- phase 2: scores = alpha @ wt (+T2), phase 3: streaming softmax ----
        if (half * 8 < tcnt) {
            float acc[8];
#pragma unroll
            for (int q = 0; q < 8; ++q) acc[q] = T2d;
            const float* wtp = wt + c;
#pragma unroll 4
            for (int cc2 = 0; cc2 < CC; ++cc2) {
                float wv = wtp[cc2 * CC];
                const float* ap = &alpha_t[cc2 * 20 + half * 8];
                float4 a0 = *(const float4*)ap;
                float4 a1 = *(const float4*)(ap + 4);
                acc[0] += a0.x * wv; acc[1] += a0.y * wv;
                acc[2] += a0.z * wv; acc[3] += a0.w * wv;
                acc[4] += a1.x * wv; acc[5] += a1.y * wv;
                acc[6] += a1.z * wv; acc[7] += a1.w * wv;
            }
#pragma unroll
            for (int q = 0; q < 8; ++q) {
                int js = half * 8 + q;
                if (js < tcnt) {
                    float s = fmaxf(acc[q], 0.f);
                    float e = __expf(s);
                    se += e;
                    ov += e * u_lds[js * CC + c];
                }
            }
        }
        __syncthreads();
    }

    if (half == 1) { sered[c] = se; ored[c] = ov; }
    __syncthreads();
    if (half == 0) {
        float S = se + sered[c];
        float O = ov + ored[c];
        out[(size_t)(b * NN + i) * CC + c] = O / S;
    }
}

extern "C" void kernel_launch(void* const* d_in, const int* in_sizes, int n_in,
                              void* d_out, int out_size, void* d_ws, size_t ws_size,
                              hipStream_t stream) {
    const float* x      = (const float*)d_in[0];
    const float* pos    = (const float*)d_in[1];
    const float* normal = (const float*)d_in[2];
    const float* W_lin  = (const float*)d_in[3];
    const float* W_src  = (const float*)d_in[4];
    const float* W_dst  = (const float*)d_in[5];
    const float* pos_w  = (const float*)d_in[6];
    const float* pos_b  = (const float*)d_in[7];
    const float* pos_g  = (const float*)d_in[8];
    const float* pos_bb = (const float*)d_in[9];
    const float* pos_m  = (const float*)d_in[10];
    const float* pos_v  = (const float*)d_in[11];
    const float* attn_w = (const float*)d_in[12];
    const float* attn_b = (const float*)d_in[13];
    const float* attn_g = (const float*)d_in[14];
    const float* attn_bb= (const float*)d_in[15];
    const float* attn_m = (const float*)d_in[16];
    const float* attn_v = (const float*)d_in[17];
    const int*   rptr   = (const int*)d_in[18];
    float* ws  = (float*)d_ws;
    float* out = (float*)d_out;

    prep_kernel<<<dim3(385), dim3(256), 0, stream>>>(
        x, W_lin, W_src, W_dst, pos_w, pos_b, pos_g, pos_bb, pos_m, pos_v,
        attn_w, attn_b, attn_g, attn_bb, attn_m, attn_v, ws);
    main_kernel<<<dim3(2048), dim3(256), 0, stream>>>(pos, normal, rptr, ws, out);
}